// Round 3
// baseline (280.074 us; speedup 1.0000x reference)
//
#include <hip/hip_runtime.h>

// x: (2,64,32,32,32) f32; N = 2048 rows of (C=64, L=32)
// qkv(bf16): (N,128,32); qk(bf16): (N*8,32,32); oraw(bf16): (N,128,32)

__device__ __forceinline__ float bf2f(unsigned short u) {
    union { unsigned int i; float f; } x; x.i = ((unsigned int)u) << 16; return x.f;
}
__device__ __forceinline__ unsigned short f2bf(float f) {
    union { float f; unsigned int i; } x; x.f = f;
    unsigned int r = x.i + 0x7FFFu + ((x.i >> 16) & 1u);
    return (unsigned short)(r >> 16);
}
__device__ __forceinline__ ushort4 f2bf4(float a, float b, float c, float d) {
    return make_ushort4(f2bf(a), f2bf(b), f2bf(c), f2bf(d));
}

// sum across each 16-lane DPP row via row_ror (VALU pipe, no LDS ops)
__device__ __forceinline__ float sum16(float v) {
    int x;
    x = __builtin_amdgcn_update_dpp(0, __float_as_int(v), 0x121, 0xF, 0xF, true); v += __int_as_float(x);
    x = __builtin_amdgcn_update_dpp(0, __float_as_int(v), 0x122, 0xF, 0xF, true); v += __int_as_float(x);
    x = __builtin_amdgcn_update_dpp(0, __float_as_int(v), 0x124, 0xF, 0xF, true); v += __int_as_float(x);
    x = __builtin_amdgcn_update_dpp(0, __float_as_int(v), 0x128, 0xF, 0xF, true); v += __int_as_float(x);
    return v;
}
__device__ __forceinline__ float sum32(float v) {   // sum over aligned 32-lane group
    v = sum16(v); return v + __shfl_xor(v, 16);
}
__device__ __forceinline__ float sum64(float v) {   // full wave
    v = sum16(v); v += __shfl_xor(v, 16); return v + __shfl_xor(v, 32);
}
__device__ __forceinline__ float oct_sum(float v) { // over 8 lanes (low 3 bits)
    v += __shfl_xor(v, 1); v += __shfl_xor(v, 2); v += __shfl_xor(v, 4);
    return v;
}

// ---------------- K1: qkv = w @ x (bf16 out) + per-channel sum/sumsq ----------------
__global__ __launch_bounds__(128) void k_qkv(const float* __restrict__ x,
                                             const float* __restrict__ w,
                                             unsigned short* __restrict__ qkv,
                                             float* __restrict__ sqkv) {
    __shared__ __attribute__((aligned(16))) float xs[64 * 32];
    __shared__ __attribute__((aligned(16))) float wT[64 * 64];  // [c][o]
    __shared__ float statQ[128];
    int bid = blockIdx.x;
    int n = bid >> 1, oh = bid & 1;
    int t = threadIdx.x;
    int b = n >> 10, hw = n & 1023;
    const float* xb = x + (size_t)b * 2097152 + (hw >> 5) * 1024 + (hw & 31) * 32;
    #pragma unroll
    for (int k = 0; k < 4; ++k) {                 // xs: float4 loads
        int idx4 = t + 128 * k;
        int c = idx4 >> 3, l4 = idx4 & 7;
        *(float4*)&xs[c * 32 + 4 * l4] = *(const float4*)&xb[(size_t)c * 32768 + 4 * l4];
    }
    {                                             // wT: transposed stage
        int o = t >> 1, hf = t & 1;
        const float* wbase = w + (size_t)(oh * 64) * 64;
        #pragma unroll
        for (int k = 0; k < 8; ++k) {
            float4 w4 = *(const float4*)&wbase[o * 64 + hf * 32 + 4 * k];
            int c = hf * 32 + 4 * k;
            wT[(c + 0) * 64 + o] = w4.x; wT[(c + 1) * 64 + o] = w4.y;
            wT[(c + 2) * 64 + o] = w4.z; wT[(c + 3) * 64 + o] = w4.w;
        }
    }
    __syncthreads();
    int ti = t >> 3, tj = t & 7;
    float acc[4][4] = {};
    #pragma unroll 8
    for (int c = 0; c < 64; ++c) {
        float4 xv = *(const float4*)&xs[c * 32 + 4 * tj];
        float4 w4 = *(const float4*)&wT[c * 64 + 4 * ti];    // broadcast
        float xa[4] = {xv.x, xv.y, xv.z, xv.w};
        float wa[4] = {w4.x, w4.y, w4.z, w4.w};
        #pragma unroll
        for (int oo = 0; oo < 4; ++oo)
            #pragma unroll
            for (int e = 0; e < 4; ++e) acc[oo][e] += wa[oo] * xa[e];
    }
    unsigned short* qn = qkv + (size_t)n * 4096 + oh * 2048;
    #pragma unroll
    for (int oo = 0; oo < 4; ++oo) {
        int o = 4 * ti + oo;
        *(ushort4*)(qn + o * 32 + 4 * tj) = f2bf4(acc[oo][0], acc[oo][1], acc[oo][2], acc[oo][3]);
        float s1 = acc[oo][0] + acc[oo][1] + acc[oo][2] + acc[oo][3];
        float s2 = acc[oo][0]*acc[oo][0] + acc[oo][1]*acc[oo][1]
                 + acc[oo][2]*acc[oo][2] + acc[oo][3]*acc[oo][3];
        s1 = oct_sum(s1); s2 = oct_sum(s2);
        if (tj == 0) { statQ[o * 2] = s1; statQ[o * 2 + 1] = s2; }
    }
    __syncthreads();
    if (t < 128) {
        int ch = oh * 64 + (t >> 1);
        atomicAdd(&sqkv[((t & 1) ? 128 : 0) + ch], statQ[t]);
    }
}

// ---------------- K2: sim stats + write qk (bf16) ----------------
// grid 8192, block 128 = 2 waves; wave wv handles n = wv*1024 + (bid>>3), g = bid&7
__global__ __launch_bounds__(128) void k_sim(const unsigned short* __restrict__ qkv,
                                             const float* __restrict__ rel,
                                             const float* __restrict__ sqkv,
                                             const float* __restrict__ bqg,
                                             const float* __restrict__ bqb,
                                             unsigned short* __restrict__ qk_g,
                                             float* __restrict__ ssim) {
    __shared__ float relS[8 * 64];
    __shared__ __attribute__((aligned(16))) float qkT[2][32 * 8];   // [i][c]
    __shared__ __attribute__((aligned(16))) float qeS[2][32 * 36];
    __shared__ __attribute__((aligned(16))) float keS[2][32 * 36];
    __shared__ float statS[2][6];
    int t = threadIdx.x;
    int wv = t >> 6, l = t & 63;
    int bid = blockIdx.x;
    int g = bid & 7;
    int n = wv * 1024 + (bid >> 3);
    #pragma unroll
    for (int k = 0; k < 4; ++k) {
        int slot = t + 128 * k;
        int c = slot >> 6, d = slot & 63;
        relS[slot] = (d < 63) ? rel[c * 63 + d] : 0.0f;
    }
    {   // stage q/k-hat transposed [i][c]
        int i = l & 31, chalf = l >> 5;
        const unsigned short* qn = qkv + (size_t)n * 4096 + g * 512;
        float vals[4];
        #pragma unroll
        for (int e = 0; e < 4; ++e) {
            int c = 4 * chalf + e, ch = g * 16 + c;
            float mu = sqkv[ch] * (1.0f / 65536.0f);
            float var = sqkv[128 + ch] * (1.0f / 65536.0f) - mu * mu;
            float aa = bqg[ch] * rsqrtf(var + 1e-5f);
            float bb = bqb[ch] - mu * aa;
            vals[e] = aa * bf2f(qn[c * 32 + i]) + bb;
        }
        *(float4*)&qkT[wv][i * 8 + 4 * chalf] = make_float4(vals[0], vals[1], vals[2], vals[3]);
    }
    __syncthreads();
    int j = l & 31, h = l >> 5;
    float sqe = 0, sqe2 = 0, ske = 0, ske2 = 0;
    #pragma unroll 4
    for (int ii = 0; ii < 16; ++ii) {
        int i = h + 2 * ii;
        int dd = i - j + 31;
        float4 q4 = *(const float4*)&qkT[wv][i * 8];        // broadcast
        float4 k4 = *(const float4*)&qkT[wv][i * 8 + 4];
        float qe = q4.x * relS[dd] + q4.y * relS[64 + dd]
                 + q4.z * relS[128 + dd] + q4.w * relS[192 + dd];
        float ke = k4.x * relS[256 + dd] + k4.y * relS[320 + dd]
                 + k4.z * relS[384 + dd] + k4.w * relS[448 + dd];
        qeS[wv][i * 36 + j] = qe;
        keS[wv][i * 36 + j] = ke;
        sqe += qe; sqe2 += qe * qe; ske += ke; ske2 += ke * ke;
    }
    // qk matmul, 4x4 register tile (broadcast b128 reads)
    int ti = l >> 3, tj = l & 7;
    float acc[4][4] = {};
    #pragma unroll 8
    for (int p = 0; p < 32; ++p) {
        float4 q4 = *(const float4*)&qeS[wv][p * 36 + 4 * ti];
        float4 k4 = *(const float4*)&keS[wv][p * 36 + 4 * tj];
        float qa[4] = {q4.x, q4.y, q4.z, q4.w};
        float ka[4] = {k4.x, k4.y, k4.z, k4.w};
        #pragma unroll
        for (int a = 0; a < 4; ++a)
            #pragma unroll
            for (int b2 = 0; b2 < 4; ++b2) acc[a][b2] += qa[a] * ka[b2];
    }
    unsigned short* qkp = qk_g + (size_t)(n * 8 + g) * 1024;
    float s1 = 0, s2 = 0;
    #pragma unroll
    for (int a = 0; a < 4; ++a) {
        *(ushort4*)(qkp + (4 * ti + a) * 32 + 4 * tj) =
            f2bf4(acc[a][0], acc[a][1], acc[a][2], acc[a][3]);
        #pragma unroll
        for (int b2 = 0; b2 < 4; ++b2) { s1 += acc[a][b2]; s2 += acc[a][b2] * acc[a][b2]; }
    }
    s1 = sum64(s1); s2 = sum64(s2);
    sqe = sum64(sqe); sqe2 = sum64(sqe2);
    ske = sum64(ske); ske2 = sum64(ske2);
    if (l == 0) {
        statS[wv][0] = s1;  statS[wv][1] = s2;
        statS[wv][2] = sqe; statS[wv][3] = sqe2;
        statS[wv][4] = ske; statS[wv][5] = ske2;
    }
    __syncthreads();
    if (t < 6) {
        float tot = statS[0][t] + statS[1][t];
        int base = (t >> 1) * 8 + ((t & 1) ? 24 : 0);
        atomicAdd(&ssim[base + g], tot);
    }
}

// ---------------- K3: attention (qk from global, no matmul) ----------------
__global__ __launch_bounds__(256) void k_attn(const unsigned short* __restrict__ qkv,
                                              const float* __restrict__ rel,
                                              const float* __restrict__ sqkv,
                                              const float* __restrict__ bqg,
                                              const float* __restrict__ bqb,
                                              const unsigned short* __restrict__ qk_g,
                                              const float* __restrict__ ssim,
                                              const float* __restrict__ bsg,
                                              const float* __restrict__ bsb,
                                              unsigned short* __restrict__ oraw,
                                              float* __restrict__ sout) {
    __shared__ float relS[16 * 64];
    __shared__ __attribute__((aligned(16))) float qkT[4][32 * 8];   // [i][c] q/k-hat
    __shared__ __attribute__((aligned(16))) float vSt[4][32 * 8];   // [j][c] v-hat
    __shared__ float pS[4][32 * 33];
    __shared__ float statO[4][32];
    int t = threadIdx.x;
    int wv = t >> 6, l = t & 63;
    int bid = blockIdx.x;
    int g = bid & 7;
    int n = wv * 512 + (bid >> 3);
    float aQK, aQE, aKE, csum;
    {
        float m0 = ssim[g] * (1.0f / 2097152.0f);
        float v0 = ssim[24 + g] * (1.0f / 2097152.0f) - m0 * m0;
        aQK = bsg[g] * rsqrtf(v0 + 1e-5f);
        float b0 = bsb[g] - m0 * aQK;
        float m1 = ssim[8 + g] * (1.0f / 2097152.0f);
        float v1 = ssim[32 + g] * (1.0f / 2097152.0f) - m1 * m1;
        aQE = bsg[8 + g] * rsqrtf(v1 + 1e-5f);
        float b1 = bsb[8 + g] - m1 * aQE;
        float m2 = ssim[16 + g] * (1.0f / 2097152.0f);
        float v2 = ssim[40 + g] * (1.0f / 2097152.0f) - m2 * m2;
        aKE = bsg[16 + g] * rsqrtf(v2 + 1e-5f);
        float b2 = bsb[16 + g] - m2 * aKE;
        csum = b0 + b1 + b2;
    }
    int j = l & 31, h = l >> 5;
    // preload qk tile (global, before barrier)
    unsigned short qkraw[16];
    const unsigned short* qkp = qk_g + (size_t)(n * 8 + g) * 1024;
    #pragma unroll
    for (int ii = 0; ii < 16; ++ii) qkraw[ii] = qkp[(h + 2 * ii) * 32 + j];
    #pragma unroll
    for (int k = 0; k < 4; ++k) {
        int slot = t + 256 * k;
        int c = slot >> 6, d = slot & 63;
        relS[slot] = (d < 63) ? rel[c * 63 + d] : 0.0f;
    }
    {   // stage q/k-hat (ch 0..7) and v-hat (ch 8..15), transposed
        const unsigned short* qn = qkv + (size_t)n * 4096 + g * 512;
        float va[4], vb[4];
        #pragma unroll
        for (int e = 0; e < 4; ++e) {
            int c = 4 * h + e, ch = g * 16 + c;
            float mu = sqkv[ch] * (1.0f / 65536.0f);
            float var = sqkv[128 + ch] * (1.0f / 65536.0f) - mu * mu;
            float aa = bqg[ch] * rsqrtf(var + 1e-5f);
            float bb = bqb[ch] - mu * aa;
            va[e] = aa * bf2f(qn[c * 32 + j]) + bb;
            int cv = 8 + 4 * h + e, chv = g * 16 + cv;
            float muv = sqkv[chv] * (1.0f / 65536.0f);
            float varv = sqkv[128 + chv] * (1.0f / 65536.0f) - muv * muv;
            float av = bqg[chv] * rsqrtf(varv + 1e-5f);
            float bv = bqb[chv] - muv * av;
            vb[e] = av * bf2f(qn[cv * 32 + j]) + bv;
        }
        *(float4*)&qkT[wv][j * 8 + 4 * h] = make_float4(va[0], va[1], va[2], va[3]);
        *(float4*)&vSt[wv][j * 8 + 4 * h] = make_float4(vb[0], vb[1], vb[2], vb[3]);
    }
    __syncthreads();
    // scores + softmax (no max subtract: BN-bounded scores)
    #pragma unroll 4
    for (int ii = 0; ii < 16; ++ii) {
        int i = h + 2 * ii;
        int dd = i - j + 31;
        float4 q4 = *(const float4*)&qkT[wv][i * 8];        // broadcast
        float4 k4 = *(const float4*)&qkT[wv][i * 8 + 4];
        float qe = q4.x * relS[dd] + q4.y * relS[64 + dd]
                 + q4.z * relS[128 + dd] + q4.w * relS[192 + dd];
        float ke = k4.x * relS[256 + dd] + k4.y * relS[320 + dd]
                 + k4.z * relS[384 + dd] + k4.w * relS[448 + dd];
        float s = aQK * bf2f(qkraw[ii]) + aQE * qe + aKE * ke + csum;
        float e = __expf(s);
        float den = sum32(e);
        pS[wv][i * 33 + j] = e * __frcp_rn(den);
    }
    // PV (same-wave pS, no barrier needed)
    int i2 = j, h2 = h;
    float am[4] = {}, ame[4] = {};
    #pragma unroll 4
    for (int jj = 0; jj < 32; ++jj) {
        float pv = pS[wv][i2 * 33 + jj];
        int dd = i2 - jj + 31;
        float4 v4 = *(const float4*)&vSt[wv][jj * 8 + 4 * h2];  // broadcast
        am[0] += pv * v4.x; am[1] += pv * v4.y; am[2] += pv * v4.z; am[3] += pv * v4.w;
        ame[0] += pv * relS[(8 + 4 * h2) * 64 + dd];
        ame[1] += pv * relS[(9 + 4 * h2) * 64 + dd];
        ame[2] += pv * relS[(10 + 4 * h2) * 64 + dd];
        ame[3] += pv * relS[(11 + 4 * h2) * 64 + dd];
    }
    unsigned short* on = oraw + (size_t)n * 4096 + g * 512;
    #pragma unroll
    for (int cc = 0; cc < 4; ++cc) {
        int c = 4 * h2 + cc;
        on[(2 * c) * 32 + i2] = f2bf(am[cc]);
        on[(2 * c + 1) * 32 + i2] = f2bf(ame[cc]);
    }
    #pragma unroll
    for (int cc = 0; cc < 4; ++cc) {
        float a1 = sum32(am[cc]);
        float a2 = sum32(am[cc] * am[cc]);
        float e1 = sum32(ame[cc]);
        float e2 = sum32(ame[cc] * ame[cc]);
        if (i2 == 0) {
            int c = 4 * h2 + cc;
            statO[wv][c * 4 + 0] = a1; statO[wv][c * 4 + 1] = a2;
            statO[wv][c * 4 + 2] = e1; statO[wv][c * 4 + 3] = e2;
        }
    }
    __syncthreads();
    if (t < 32) {
        int c = t >> 2, k = t & 3;
        float tot = statO[0][c * 4 + k] + statO[1][c * 4 + k]
                  + statO[2][c * 4 + k] + statO[3][c * 4 + k];
        int och = g * 16 + 2 * c + ((k >> 1) & 1);
        atomicAdd(&sout[((k & 1) ? 128 : 0) + och], tot);
    }
}

// ---------------- K4: out BN + pair-sum + transpose ----------------
__global__ __launch_bounds__(256) void k_out(const unsigned short* __restrict__ oraw,
                                             const float* __restrict__ sout,
                                             const float* __restrict__ bog,
                                             const float* __restrict__ bob,
                                             float* __restrict__ out) {
    int gid = blockIdx.x * 256 + threadIdx.x;
    int l4 = gid & 7;
    int rest = gid >> 3;
    int w2 = rest & 31; rest >>= 5;
    int hh = rest & 31; rest >>= 5;
    int oc = rest & 63;
    int b = rest >> 6;
    int n = b * 1024 + hh * 32 + w2;
    int c0 = 2 * oc, c1 = 2 * oc + 1;
    float mu0 = sout[c0] * (1.0f / 65536.0f);
    float v0 = sout[128 + c0] * (1.0f / 65536.0f) - mu0 * mu0;
    float a0 = bog[c0] * rsqrtf(v0 + 1e-5f);
    float b0 = bob[c0] - mu0 * a0;
    float mu1 = sout[c1] * (1.0f / 65536.0f);
    float v1 = sout[128 + c1] * (1.0f / 65536.0f) - mu1 * mu1;
    float a1 = bog[c1] * rsqrtf(v1 + 1e-5f);
    float b1 = bob[c1] - mu1 * a1;
    float cc = b0 + b1;
    const ushort4 r0 = *(const ushort4*)(oraw + (size_t)n * 4096 + oc * 64 + l4 * 4);
    const ushort4 r1 = *(const ushort4*)(oraw + (size_t)n * 4096 + oc * 64 + 32 + l4 * 4);
    float4 o;
    o.x = a0 * bf2f(r0.x) + a1 * bf2f(r1.x) + cc;
    o.y = a0 * bf2f(r0.y) + a1 * bf2f(r1.y) + cc;
    o.z = a0 * bf2f(r0.z) + a1 * bf2f(r1.z) + cc;
    o.w = a0 * bf2f(r0.w) + a1 * bf2f(r1.w) + cc;
    *((float4*)out + gid) = o;
}

extern "C" void kernel_launch(void* const* d_in, const int* in_sizes, int n_in,
                              void* d_out, int out_size, void* d_ws, size_t ws_size,
                              hipStream_t stream) {
    const float* x   = (const float*)d_in[0];
    const float* w   = (const float*)d_in[1];
    const float* bqg = (const float*)d_in[2];
    const float* bqb = (const float*)d_in[3];
    const float* bsg = (const float*)d_in[4];
    const float* bsb = (const float*)d_in[5];
    const float* bog = (const float*)d_in[6];
    const float* bob = (const float*)d_in[7];
    const float* rel = (const float*)d_in[8];

    unsigned short* qkv_bf  = (unsigned short*)d_ws;       // 8,388,608
    unsigned short* qk_bf   = qkv_bf + 8388608;            // 16,777,216
    unsigned short* oraw_bf = qk_bf + 16777216;            // 8,388,608
    float* stats = (float*)(oraw_bf + 8388608);
    float* sqkv  = stats;          // 256
    float* ssim  = stats + 256;    // 48
    float* sout  = stats + 304;    // 256

    hipMemsetAsync(stats, 0, 560 * sizeof(float), stream);

    k_qkv<<<4096, 128, 0, stream>>>(x, w, qkv_bf, sqkv);
    k_sim<<<8192, 128, 0, stream>>>(qkv_bf, rel, sqkv, bqg, bqb, qk_bf, ssim);
    k_attn<<<4096, 256, 0, stream>>>(qkv_bf, rel, sqkv, bqg, bqb, qk_bf, ssim, bsg, bsb, oraw_bf, sout);
    k_out<<<4096, 256, 0, stream>>>(oraw_bf, sout, bog, bob, (float*)d_out);
}

// Round 4
// 201.228 us; speedup vs baseline: 1.3918x; 1.3918x over previous
//
#include <hip/hip_runtime.h>

// x: (2,64,32,32,32) f32; N = 2048 rows of (C=64, L=32)
// qkv(f32): (N,128,32); oraw(f32): (N,128,32)
// Pair = (n,g): 16384. k_sim/k_attn: 2048 blocks x 8 waves, 1 pair/wave.

typedef __attribute__((ext_vector_type(8))) short bf16x8;
typedef __attribute__((ext_vector_type(16))) float f32x16;

__device__ __forceinline__ float bf2f(unsigned short u) {
    union { unsigned int i; float f; } x; x.i = ((unsigned int)u) << 16; return x.f;
}
__device__ __forceinline__ unsigned short f2bf(float f) {
    union { float f; unsigned int i; } x; x.f = f;
    unsigned int r = x.i + 0x7FFFu + ((x.i >> 16) & 1u);
    return (unsigned short)(r >> 16);
}

__device__ __forceinline__ float sum16(float v) {
    int x;
    x = __builtin_amdgcn_update_dpp(0, __float_as_int(v), 0x121, 0xF, 0xF, true); v += __int_as_float(x);
    x = __builtin_amdgcn_update_dpp(0, __float_as_int(v), 0x122, 0xF, 0xF, true); v += __int_as_float(x);
    x = __builtin_amdgcn_update_dpp(0, __float_as_int(v), 0x124, 0xF, 0xF, true); v += __int_as_float(x);
    x = __builtin_amdgcn_update_dpp(0, __float_as_int(v), 0x128, 0xF, 0xF, true); v += __int_as_float(x);
    return v;
}
__device__ __forceinline__ float sum32(float v) {
    v = sum16(v); return v + __shfl_xor(v, 16);
}
__device__ __forceinline__ float sum64(float v) {
    v = sum16(v); v += __shfl_xor(v, 16); return v + __shfl_xor(v, 32);
}
__device__ __forceinline__ float oct_sum(float v) {
    v += __shfl_xor(v, 1); v += __shfl_xor(v, 2); v += __shfl_xor(v, 4);
    return v;
}

// ---------------- K0: build bf16 emb tables ----------------
// gemb[0..18431]        : P-orientation [c=0..15][a=0..31][b=0..35] = rel[c][a-b+31] (b<32)
// gemb[18432..27647]    : T-orientation [c=0..7 ][y=0..31][x=0..35] = rel[c][x-y+31] (x<32)
__global__ __launch_bounds__(512) void k_emb(const float* __restrict__ rel,
                                             unsigned short* __restrict__ gemb) {
    int t = threadIdx.x;
    for (int idx = t; idx < 18432; idx += 512) {
        int c = idx / 1152, rm = idx % 1152, a = rm / 36, b = rm % 36;
        gemb[idx] = (b < 32) ? f2bf(rel[c * 63 + a - b + 31]) : (unsigned short)0;
    }
    for (int idx = t; idx < 9216; idx += 512) {
        int c = idx / 1152, rm = idx % 1152, y = rm / 36, x = rm % 36;
        gemb[18432 + idx] = (x < 32) ? f2bf(rel[c * 63 + x - y + 31]) : (unsigned short)0;
    }
}

// ---------------- K1: qkv = w @ x (f32) + per-channel sum/sumsq ----------------
__global__ __launch_bounds__(128) void k_qkv(const float* __restrict__ x,
                                             const float* __restrict__ w,
                                             float* __restrict__ qkv,
                                             float* __restrict__ sqkv) {
    __shared__ __attribute__((aligned(16))) float xs[64 * 32];
    __shared__ __attribute__((aligned(16))) float wT[64 * 64];  // [c][o]
    __shared__ float statQ[128];
    int bid = blockIdx.x;
    int n = bid >> 1, oh = bid & 1;
    int t = threadIdx.x;
    int b = n >> 10, hw = n & 1023;
    const float* xb = x + (size_t)b * 2097152 + (hw >> 5) * 1024 + (hw & 31) * 32;
    #pragma unroll
    for (int k = 0; k < 4; ++k) {
        int idx4 = t + 128 * k;
        int c = idx4 >> 3, l4 = idx4 & 7;
        *(float4*)&xs[c * 32 + 4 * l4] = *(const float4*)&xb[(size_t)c * 32768 + 4 * l4];
    }
    {
        int o = t >> 1, hf = t & 1;
        const float* wbase = w + (size_t)(oh * 64) * 64;
        #pragma unroll
        for (int k = 0; k < 8; ++k) {
            float4 w4 = *(const float4*)&wbase[o * 64 + hf * 32 + 4 * k];
            int c = hf * 32 + 4 * k;
            wT[(c + 0) * 64 + o] = w4.x; wT[(c + 1) * 64 + o] = w4.y;
            wT[(c + 2) * 64 + o] = w4.z; wT[(c + 3) * 64 + o] = w4.w;
        }
    }
    __syncthreads();
    int ti = t >> 3, tj = t & 7;
    float acc[4][4] = {};
    #pragma unroll 8
    for (int c = 0; c < 64; ++c) {
        float4 xv = *(const float4*)&xs[c * 32 + 4 * tj];
        float4 w4 = *(const float4*)&wT[c * 64 + 4 * ti];
        float xa[4] = {xv.x, xv.y, xv.z, xv.w};
        float wa[4] = {w4.x, w4.y, w4.z, w4.w};
        #pragma unroll
        for (int oo = 0; oo < 4; ++oo)
            #pragma unroll
            for (int e = 0; e < 4; ++e) acc[oo][e] += wa[oo] * xa[e];
    }
    float* qn = qkv + (size_t)n * 4096 + oh * 2048;
    #pragma unroll
    for (int oo = 0; oo < 4; ++oo) {
        int o = 4 * ti + oo;
        *(float4*)(qn + o * 32 + 4 * tj) =
            make_float4(acc[oo][0], acc[oo][1], acc[oo][2], acc[oo][3]);
        float s1 = acc[oo][0] + acc[oo][1] + acc[oo][2] + acc[oo][3];
        float s2 = acc[oo][0]*acc[oo][0] + acc[oo][1]*acc[oo][1]
                 + acc[oo][2]*acc[oo][2] + acc[oo][3]*acc[oo][3];
        s1 = oct_sum(s1); s2 = oct_sum(s2);
        if (tj == 0) { statQ[o * 2] = s1; statQ[o * 2 + 1] = s2; }
    }
    __syncthreads();
    if (t < 128) {
        int ch = oh * 64 + (t >> 1);
        atomicAdd(&sqkv[((t & 1) ? 128 : 0) + ch], statQ[t]);
    }
}

// ---------------- K2: sim stats via MFMA qk ----------------
__global__ __launch_bounds__(512, 4) void k_sim(const float* __restrict__ qkv,
                                                const unsigned short* __restrict__ gemb,
                                                const float* __restrict__ sqkv,
                                                const float* __restrict__ bqg,
                                                const float* __restrict__ bqb,
                                                float* __restrict__ psim) {
    __shared__ __attribute__((aligned(16))) unsigned short embT[9216];
    __shared__ __attribute__((aligned(16))) float qkT[8][256];  // per wave [32 p][8 c]
    __shared__ float statw[8][6];
    int t = threadIdx.x, wv = t >> 6, l = t & 63;
    int g = blockIdx.x & 7, nb = blockIdx.x >> 3;
    int n = nb * 8 + wv;
    int li = l & 31, h = l >> 5;
    {
        const ushort4* gs = (const ushort4*)(gemb + 18432);
        ushort4* ld = (ushort4*)embT;
        for (int idx = t; idx < 2304; idx += 512) ld[idx] = gs[idx];
    }
    {
        int ch = l >> 3, i0 = (l & 7) * 4;
        const float* qn = qkv + (size_t)n * 4096 + g * 512;
        float4 q4 = *(const float4*)(qn + ch * 32 + i0);
        int cc = g * 16 + ch;
        float mu = sqkv[cc] * (1.0f / 65536.0f);
        float var = sqkv[128 + cc] * (1.0f / 65536.0f) - mu * mu;
        float aa = bqg[cc] * rsqrtf(var + 1e-5f);
        float bb = bqb[cc] - mu * aa;
        float* qT = qkT[wv];
        qT[(i0 + 0) * 8 + ch] = aa * q4.x + bb;
        qT[(i0 + 1) * 8 + ch] = aa * q4.y + bb;
        qT[(i0 + 2) * 8 + ch] = aa * q4.z + bb;
        qT[(i0 + 3) * 8 + ch] = aa * q4.w + bb;
    }
    __syncthreads();
    bf16x8 fQE[2], fKE[2];
    float sqe = 0, sqe2 = 0, ske = 0, ske2 = 0;
    #pragma unroll
    for (int s = 0; s < 2; ++s) {
        #pragma unroll
        for (int blk = 0; blk < 2; ++blk) {
            int p0 = 16 * s + 4 * h + 8 * blk;
            float qrm[4][4], krm[4][4];
            #pragma unroll
            for (int e2 = 0; e2 < 4; ++e2) {
                float4 tq = *(const float4*)&qkT[wv][(p0 + e2) * 8];
                float4 tk = *(const float4*)&qkT[wv][(p0 + e2) * 8 + 4];
                qrm[e2][0] = tq.x; qrm[e2][1] = tq.y; qrm[e2][2] = tq.z; qrm[e2][3] = tq.w;
                krm[e2][0] = tk.x; krm[e2][1] = tk.y; krm[e2][2] = tk.z; krm[e2][3] = tk.w;
            }
            float qe[4] = {}, ke[4] = {};
            #pragma unroll
            for (int c = 0; c < 4; ++c) {
                ushort4 eq = *(const ushort4*)&embT[(c * 32 + li) * 36 + p0];
                ushort4 ek = *(const ushort4*)&embT[((4 + c) * 32 + li) * 36 + p0];
                qe[0] += qrm[0][c] * bf2f(eq.x); qe[1] += qrm[1][c] * bf2f(eq.y);
                qe[2] += qrm[2][c] * bf2f(eq.z); qe[3] += qrm[3][c] * bf2f(eq.w);
                ke[0] += krm[0][c] * bf2f(ek.x); ke[1] += krm[1][c] * bf2f(ek.y);
                ke[2] += krm[2][c] * bf2f(ek.z); ke[3] += krm[3][c] * bf2f(ek.w);
            }
            #pragma unroll
            for (int e2 = 0; e2 < 4; ++e2) {
                sqe += qe[e2]; sqe2 += qe[e2] * qe[e2];
                ske += ke[e2]; ske2 += ke[e2] * ke[e2];
                fQE[s][4 * blk + e2] = (short)f2bf(qe[e2]);
                fKE[s][4 * blk + e2] = (short)f2bf(ke[e2]);
            }
        }
    }
    f32x16 D = {};
    D = __builtin_amdgcn_mfma_f32_32x32x16_bf16(fKE[0], fQE[0], D, 0, 0, 0);
    D = __builtin_amdgcn_mfma_f32_32x32x16_bf16(fKE[1], fQE[1], D, 0, 0, 0);
    float s1 = 0, s2 = 0;
    #pragma unroll
    for (int r = 0; r < 16; ++r) { s1 += D[r]; s2 += D[r] * D[r]; }
    s1 = sum64(s1); s2 = sum64(s2);
    sqe = sum64(sqe); sqe2 = sum64(sqe2);
    ske = sum64(ske); ske2 = sum64(ske2);
    if (l == 0) {
        statw[wv][0] = s1;  statw[wv][1] = s2;
        statw[wv][2] = sqe; statw[wv][3] = sqe2;
        statw[wv][4] = ske; statw[wv][5] = ske2;
    }
    __syncthreads();
    if (t < 6) {
        float tot = 0;
        #pragma unroll
        for (int w2 = 0; w2 < 8; ++w2) tot += statw[w2][t];
        psim[blockIdx.x * 8 + t] = tot;
    }
}

// ---------------- K3: reduce sim partials ----------------
__global__ __launch_bounds__(64) void red_sim(const float* __restrict__ psim,
                                              float* __restrict__ ssim) {
    int t = threadIdx.x;
    if (t >= 48) return;
    int g = t / 6, s = t % 6;
    float acc = 0;
    #pragma unroll 8
    for (int nb = 0; nb < 256; ++nb) acc += psim[(nb * 8 + g) * 8 + s];
    const int base[6] = {0, 24, 8, 32, 16, 40};
    ssim[base[s] + g] = acc;
}

// ---------------- K4: attention (MFMA qk + MFMA PV) ----------------
__global__ __launch_bounds__(512, 4) void k_attn(const float* __restrict__ qkv,
                                                 const unsigned short* __restrict__ gemb,
                                                 const float* __restrict__ sqkv,
                                                 const float* __restrict__ bqg,
                                                 const float* __restrict__ bqb,
                                                 const float* __restrict__ ssim,
                                                 const float* __restrict__ bsg,
                                                 const float* __restrict__ bsb,
                                                 float* __restrict__ oraw,
                                                 float* __restrict__ sout) {
    __shared__ __attribute__((aligned(16))) unsigned short embA[27648]; // P[18432] + T[9216]
    __shared__ __attribute__((aligned(16))) float qkT[8][256];
    __shared__ __attribute__((aligned(16))) float vhT[8][256];
    __shared__ float statw[8][32];
    int t = threadIdx.x, wv = t >> 6, l = t & 63;
    int g = blockIdx.x & 7, nb = blockIdx.x >> 3;
    int n = nb * 8 + wv;
    int li = l & 31, h = l >> 5;
    float aQK, aQE, aKE, csum;
    {
        float m0 = ssim[g] * (1.0f / 2097152.0f);
        float v0 = ssim[24 + g] * (1.0f / 2097152.0f) - m0 * m0;
        aQK = bsg[g] * rsqrtf(v0 + 1e-5f);
        float b0 = bsb[g] - m0 * aQK;
        float m1 = ssim[8 + g] * (1.0f / 2097152.0f);
        float v1 = ssim[32 + g] * (1.0f / 2097152.0f) - m1 * m1;
        aQE = bsg[8 + g] * rsqrtf(v1 + 1e-5f);
        float b1 = bsb[8 + g] - m1 * aQE;
        float m2 = ssim[16 + g] * (1.0f / 2097152.0f);
        float v2 = ssim[40 + g] * (1.0f / 2097152.0f) - m2 * m2;
        aKE = bsg[16 + g] * rsqrtf(v2 + 1e-5f);
        float b2 = bsb[16 + g] - m2 * aKE;
        csum = b0 + b1 + b2;
    }
    {
        const ushort4* gs = (const ushort4*)gemb;
        ushort4* ld = (ushort4*)embA;
        for (int idx = t; idx < 6912; idx += 512) ld[idx] = gs[idx];
    }
    {
        int ch = l >> 3, i0 = (l & 7) * 4;
        const float* qn = qkv + (size_t)n * 4096 + g * 512;
        float4 q4 = *(const float4*)(qn + ch * 32 + i0);
        int cc = g * 16 + ch;
        float mu = sqkv[cc] * (1.0f / 65536.0f);
        float var = sqkv[128 + cc] * (1.0f / 65536.0f) - mu * mu;
        float aa = bqg[cc] * rsqrtf(var + 1e-5f);
        float bb = bqb[cc] - mu * aa;
        float* qT = qkT[wv];
        qT[(i0 + 0) * 8 + ch] = aa * q4.x + bb;
        qT[(i0 + 1) * 8 + ch] = aa * q4.y + bb;
        qT[(i0 + 2) * 8 + ch] = aa * q4.z + bb;
        qT[(i0 + 3) * 8 + ch] = aa * q4.w + bb;
        float4 v4 = *(const float4*)(qn + (8 + ch) * 32 + i0);
        int cv = g * 16 + 8 + ch;
        float muv = sqkv[cv] * (1.0f / 65536.0f);
        float varv = sqkv[128 + cv] * (1.0f / 65536.0f) - muv * muv;
        float av = bqg[cv] * rsqrtf(varv + 1e-5f);
        float bv = bqb[cv] - muv * av;
        float* vT = vhT[wv];
        vT[(i0 + 0) * 8 + ch] = av * v4.x + bv;
        vT[(i0 + 1) * 8 + ch] = av * v4.y + bv;
        vT[(i0 + 2) * 8 + ch] = av * v4.z + bv;
        vT[(i0 + 3) * 8 + ch] = av * v4.w + bv;
    }
    __syncthreads();
    const unsigned short* embT = embA + 18432;
    // qk via MFMA (D[j][i] = qk[i][j])
    bf16x8 fQE[2], fKE[2];
    #pragma unroll
    for (int s = 0; s < 2; ++s) {
        #pragma unroll
        for (int blk = 0; blk < 2; ++blk) {
            int p0 = 16 * s + 4 * h + 8 * blk;
            float qrm[4][4], krm[4][4];
            #pragma unroll
            for (int e2 = 0; e2 < 4; ++e2) {
                float4 tq = *(const float4*)&qkT[wv][(p0 + e2) * 8];
                float4 tk = *(const float4*)&qkT[wv][(p0 + e2) * 8 + 4];
                qrm[e2][0] = tq.x; qrm[e2][1] = tq.y; qrm[e2][2] = tq.z; qrm[e2][3] = tq.w;
                krm[e2][0] = tk.x; krm[e2][1] = tk.y; krm[e2][2] = tk.z; krm[e2][3] = tk.w;
            }
            float qe[4] = {}, ke[4] = {};
            #pragma unroll
            for (int c = 0; c < 4; ++c) {
                ushort4 eq = *(const ushort4*)&embT[(c * 32 + li) * 36 + p0];
                ushort4 ek = *(const ushort4*)&embT[((4 + c) * 32 + li) * 36 + p0];
                qe[0] += qrm[0][c] * bf2f(eq.x); qe[1] += qrm[1][c] * bf2f(eq.y);
                qe[2] += qrm[2][c] * bf2f(eq.z); qe[3] += qrm[3][c] * bf2f(eq.w);
                ke[0] += krm[0][c] * bf2f(ek.x); ke[1] += krm[1][c] * bf2f(ek.y);
                ke[2] += krm[2][c] * bf2f(ek.z); ke[3] += krm[3][c] * bf2f(ek.w);
            }
            #pragma unroll
            for (int e2 = 0; e2 < 4; ++e2) {
                fQE[s][4 * blk + e2] = (short)f2bf(qe[e2]);
                fKE[s][4 * blk + e2] = (short)f2bf(ke[e2]);
            }
        }
    }
    f32x16 D = {};
    D = __builtin_amdgcn_mfma_f32_32x32x16_bf16(fKE[0], fQE[0], D, 0, 0, 0);
    D = __builtin_amdgcn_mfma_f32_32x32x16_bf16(fKE[1], fQE[1], D, 0, 0, 0);
    // lane-local qhat/khat for score terms
    float qh[4], kh[4];
    {
        float4 a4 = *(const float4*)&qkT[wv][li * 8];
        float4 b4 = *(const float4*)&qkT[wv][li * 8 + 4];
        qh[0] = a4.x; qh[1] = a4.y; qh[2] = a4.z; qh[3] = a4.w;
        kh[0] = b4.x; kh[1] = b4.y; kh[2] = b4.z; kh[3] = b4.w;
    }
    // scores + softmax over j (16 regs + partner lane)
    float pe[16];
    #pragma unroll
    for (int rq = 0; rq < 4; ++rq) {
        int j0 = 8 * rq + 4 * h;
        float qe4[4] = {}, ke4[4] = {};
        #pragma unroll
        for (int c = 0; c < 4; ++c) {
            ushort4 eq = *(const ushort4*)&embA[(c * 32 + li) * 36 + j0];
            ushort4 ek = *(const ushort4*)&embA[((4 + c) * 32 + li) * 36 + j0];
            qe4[0] += qh[c] * bf2f(eq.x); qe4[1] += qh[c] * bf2f(eq.y);
            qe4[2] += qh[c] * bf2f(eq.z); qe4[3] += qh[c] * bf2f(eq.w);
            ke4[0] += kh[c] * bf2f(ek.x); ke4[1] += kh[c] * bf2f(ek.y);
            ke4[2] += kh[c] * bf2f(ek.z); ke4[3] += kh[c] * bf2f(ek.w);
        }
        #pragma unroll
        for (int e2 = 0; e2 < 4; ++e2) {
            float sv = aQK * D[4 * rq + e2] + aQE * qe4[e2] + aKE * ke4[e2] + csum;
            pe[4 * rq + e2] = __expf(sv);
        }
    }
    float se = 0;
    #pragma unroll
    for (int r = 0; r < 16; ++r) se += pe[r];
    se += __shfl_xor(se, 32);
    float inv = __frcp_rn(se);
    #pragma unroll
    for (int r = 0; r < 16; ++r) pe[r] *= inv;
    // PV via MFMA: am[c][i] = sum_j vhat[c][j] * P[i][j]
    bf16x8 fP[2], fV[2];
    #pragma unroll
    for (int s = 0; s < 2; ++s) {
        #pragma unroll
        for (int e = 0; e < 8; ++e) {
            int r = (e & 3) + 4 * (e >> 2) + 8 * s;
            fP[s][e] = (short)f2bf(pe[r]);
            int j = 16 * s + (e & 3) + 4 * h + 8 * (e >> 2);
            float vv = vhT[wv][j * 8 + (li & 7)];
            fV[s][e] = (short)f2bf(li < 8 ? vv : 0.0f);
        }
    }
    f32x16 D2 = {};
    D2 = __builtin_amdgcn_mfma_f32_32x32x16_bf16(fV[0], fP[0], D2, 0, 0, 0);
    D2 = __builtin_amdgcn_mfma_f32_32x32x16_bf16(fV[1], fP[1], D2, 0, 0, 0);
    // ame[c][i] = sum_j P[i][j] * emb_v[c][i][j]
    float ame[8];
    #pragma unroll
    for (int c = 0; c < 8; ++c) {
        float acc = 0;
        #pragma unroll
        for (int rq = 0; rq < 4; ++rq) {
            int j0 = 8 * rq + 4 * h;
            ushort4 ev = *(const ushort4*)&embA[((8 + c) * 32 + li) * 36 + j0];
            acc += pe[4 * rq + 0] * bf2f(ev.x) + pe[4 * rq + 1] * bf2f(ev.y)
                 + pe[4 * rq + 2] * bf2f(ev.z) + pe[4 * rq + 3] * bf2f(ev.w);
        }
        ame[c] = acc + __shfl_xor(acc, 32);
    }
    // write oraw + out stats
    float* on = oraw + (size_t)n * 4096 + g * 512;
    #pragma unroll
    for (int e = 0; e < 4; ++e) {
        int c = e + 4 * h;
        float amv = D2[e];
        float amev = ame[c];
        on[(2 * c) * 32 + li] = amv;
        on[(2 * c + 1) * 32 + li] = amev;
        float x1 = sum32(amv), x2 = sum32(amv * amv);
        float y1 = sum32(amev), y2 = sum32(amev * amev);
        if (li == 0) {
            statw[wv][(2 * c) * 2 + 0] = x1;  statw[wv][(2 * c) * 2 + 1] = x2;
            statw[wv][(2 * c + 1) * 2 + 0] = y1; statw[wv][(2 * c + 1) * 2 + 1] = y2;
        }
    }
    __syncthreads();
    if (t < 32) {
        float tot = 0;
        #pragma unroll
        for (int w2 = 0; w2 < 8; ++w2) tot += statw[w2][t];
        int u = t >> 1;
        int och = g * 16 + u;
        atomicAdd(&sout[((t & 1) ? 128 : 0) + och], tot);
    }
}

// ---------------- K5: out BN (inline affine) + pair-sum + transpose ----------------
__global__ __launch_bounds__(256) void k_out(const float* __restrict__ oraw,
                                             const float* __restrict__ sout,
                                             const float* __restrict__ bog,
                                             const float* __restrict__ bob,
                                             float* __restrict__ out) {
    int gid = blockIdx.x * 256 + threadIdx.x;
    int l4 = gid & 7;
    int rest = gid >> 3;
    int w2 = rest & 31; rest >>= 5;
    int hh = rest & 31; rest >>= 5;
    int oc = rest & 63;
    int b = rest >> 6;
    int n = b * 1024 + hh * 32 + w2;
    int c0 = 2 * oc, c1 = 2 * oc + 1;
    float mu0 = sout[c0] * (1.0f / 65536.0f);
    float v0 = sout[128 + c0] * (1.0f / 65536.0f) - mu0 * mu0;
    float a0 = bog[c0] * rsqrtf(v0 + 1e-5f);
    float b0 = bob[c0] - mu0 * a0;
    float mu1 = sout[c1] * (1.0f / 65536.0f);
    float v1 = sout[128 + c1] * (1.0f / 65536.0f) - mu1 * mu1;
    float a1 = bog[c1] * rsqrtf(v1 + 1e-5f);
    float b1 = bob[c1] - mu1 * a1;
    float cc = b0 + b1;
    const float4 r0 = *(const float4*)(oraw + (size_t)n * 4096 + oc * 64 + l4 * 4);
    const float4 r1 = *(const float4*)(oraw + (size_t)n * 4096 + oc * 64 + 32 + l4 * 4);
    float4 o;
    o.x = a0 * r0.x + a1 * r1.x + cc;
    o.y = a0 * r0.y + a1 * r1.y + cc;
    o.z = a0 * r0.z + a1 * r1.z + cc;
    o.w = a0 * r0.w + a1 * r1.w + cc;
    *((float4*)out + gid) = o;
}

extern "C" void kernel_launch(void* const* d_in, const int* in_sizes, int n_in,
                              void* d_out, int out_size, void* d_ws, size_t ws_size,
                              hipStream_t stream) {
    const float* x   = (const float*)d_in[0];
    const float* w   = (const float*)d_in[1];
    const float* bqg = (const float*)d_in[2];
    const float* bqb = (const float*)d_in[3];
    const float* bsg = (const float*)d_in[4];
    const float* bsb = (const float*)d_in[5];
    const float* bog = (const float*)d_in[6];
    const float* bob = (const float*)d_in[7];
    const float* rel = (const float*)d_in[8];

    float* ws   = (float*)d_ws;
    float* qkv  = ws;                    // 8,388,608 f32
    float* oraw = ws + 8388608;          // 8,388,608 f32
    float* psim = oraw;                  // 2048*8 f32, consumed before k_attn writes oraw
    unsigned short* gemb = (unsigned short*)(ws + 16777216);   // 27,648 ushort
    float* stats = ws + 16777216 + 13824;
    float* sqkv = stats;        // 256
    float* ssim = stats + 256;  // 48
    float* sout = stats + 304;  // 256

    hipMemsetAsync(stats, 0, 560 * sizeof(float), stream);

    k_emb<<<1, 512, 0, stream>>>(rel, gemb);
    k_qkv<<<4096, 128, 0, stream>>>(x, w, qkv, sqkv);
    k_sim<<<2048, 512, 0, stream>>>(qkv, gemb, sqkv, bqg, bqb, psim);
    red_sim<<<1, 64, 0, stream>>>(psim, ssim);
    k_attn<<<2048, 512, 0, stream>>>(qkv, gemb, sqkv, bqg, bqb, ssim, bsg, bsb, oraw, sout);
    k_out<<<4096, 256, 0, stream>>>(oraw, sout, bog, bob, (float*)d_out);
}

// Round 5
// 166.312 us; speedup vs baseline: 1.6840x; 1.2099x over previous
//
#include <hip/hip_runtime.h>

// x: (2,64,32,32,32) f32; N = 2048 rows of (C=64, L=32)
// qkv(f32): (N,128,32); oraw(f32): (N,128,32)
// Pair = (n,g): 16384. k_sim/k_attn: 2048 blocks x 8 waves, 1 pair/wave.
// emb tables (f16, global, L2-hot):
//   eT2 [c2=0..3][y=0..31][x=0..35] half2 = (rel[2c2][x-y+31], rel[2c2+1][x-y+31])
//   eP2 [c2=0..3][a=0..31][b=0..35] half2 = (rel[2c2][a-b+31], rel[2c2+1][a-b+31])
//   ePv [c=0..7 ][a=0..31][b=0..35] half  =  rel[8+c][a-b+31]

typedef _Float16 f16;
typedef __attribute__((ext_vector_type(2))) _Float16 f16x2;
typedef __attribute__((ext_vector_type(8))) _Float16 f16x8;
typedef __attribute__((ext_vector_type(16))) float f32x16;

struct U4 { unsigned a[4]; };
union F8 { unsigned u[4]; f16x8 v; };

__device__ __forceinline__ U4 ld4(const unsigned* p) {
    uint4 v = *(const uint4*)p;
    U4 r; r.a[0] = v.x; r.a[1] = v.y; r.a[2] = v.z; r.a[3] = v.w;
    return r;
}
__device__ __forceinline__ f16x2 u2h(unsigned u) { return __builtin_bit_cast(f16x2, u); }

__device__ __forceinline__ float fdot2u(unsigned a, unsigned b, float c) {
#if __has_builtin(__builtin_amdgcn_fdot2)
    return __builtin_amdgcn_fdot2(u2h(a), u2h(b), c, false);
#else
    f16x2 x = u2h(a), y = u2h(b);
    return (float)x.x * (float)y.x + (float)x.y * (float)y.y + c;
#endif
}
__device__ __forceinline__ unsigned pkrtz(float a, float b) {
#if __has_builtin(__builtin_amdgcn_cvt_pkrtz)
    return __builtin_bit_cast(unsigned, __builtin_amdgcn_cvt_pkrtz(a, b));
#else
    f16x2 v; v.x = (f16)a; v.y = (f16)b;
    return __builtin_bit_cast(unsigned, v);
#endif
}

__device__ __forceinline__ float sum16(float v) {
    int x;
    x = __builtin_amdgcn_update_dpp(0, __float_as_int(v), 0x121, 0xF, 0xF, true); v += __int_as_float(x);
    x = __builtin_amdgcn_update_dpp(0, __float_as_int(v), 0x122, 0xF, 0xF, true); v += __int_as_float(x);
    x = __builtin_amdgcn_update_dpp(0, __float_as_int(v), 0x124, 0xF, 0xF, true); v += __int_as_float(x);
    x = __builtin_amdgcn_update_dpp(0, __float_as_int(v), 0x128, 0xF, 0xF, true); v += __int_as_float(x);
    return v;
}
__device__ __forceinline__ float sum32(float v) {
    v = sum16(v); return v + __shfl_xor(v, 16);
}
__device__ __forceinline__ float sum64(float v) {
    v = sum16(v); v += __shfl_xor(v, 16); return v + __shfl_xor(v, 32);
}
__device__ __forceinline__ float oct_sum(float v) {
    v += __shfl_xor(v, 1); v += __shfl_xor(v, 2); v += __shfl_xor(v, 4);
    return v;
}

// ---------------- K0: build f16 emb tables ----------------
__global__ __launch_bounds__(512) void k_emb(const float* __restrict__ rel,
                                             f16* __restrict__ gemb) {
    int t = threadIdx.x;
    for (int e = t; e < 4608; e += 512) {            // eT2
        int c2 = e / 1152, rm = e % 1152, y = rm / 36, x = rm % 36;
        f16 v0 = (f16)0, v1 = (f16)0;
        if (x < 32) {
            v0 = (f16)rel[(2 * c2) * 63 + x - y + 31];
            v1 = (f16)rel[(2 * c2 + 1) * 63 + x - y + 31];
        }
        gemb[2 * e] = v0; gemb[2 * e + 1] = v1;
    }
    for (int e = t; e < 4608; e += 512) {            // eP2 (half offset 9216)
        int c2 = e / 1152, rm = e % 1152, a = rm / 36, b = rm % 36;
        f16 v0 = (f16)0, v1 = (f16)0;
        if (b < 32) {
            v0 = (f16)rel[(2 * c2) * 63 + a - b + 31];
            v1 = (f16)rel[(2 * c2 + 1) * 63 + a - b + 31];
        }
        gemb[9216 + 2 * e] = v0; gemb[9216 + 2 * e + 1] = v1;
    }
    for (int e = t; e < 9216; e += 512) {            // ePv (half offset 18432)
        int c = e / 1152, rm = e % 1152, a = rm / 36, b = rm % 36;
        gemb[18432 + e] = (b < 32) ? (f16)rel[(8 + c) * 63 + a - b + 31] : (f16)0;
    }
}

// ---------------- K1: qkv = w @ x (f32) + per-channel sum/sumsq ----------------
__global__ __launch_bounds__(128) void k_qkv(const float* __restrict__ x,
                                             const float* __restrict__ w,
                                             float* __restrict__ qkv,
                                             float* __restrict__ sqkv) {
    __shared__ __attribute__((aligned(16))) float xs[64 * 32];
    __shared__ __attribute__((aligned(16))) float wT[64 * 64];  // [c][o]
    __shared__ float statQ[128];
    int bid = blockIdx.x;
    int n = bid >> 1, oh = bid & 1;
    int t = threadIdx.x;
    int b = n >> 10, hw = n & 1023;
    const float* xb = x + (size_t)b * 2097152 + (hw >> 5) * 1024 + (hw & 31) * 32;
    #pragma unroll
    for (int k = 0; k < 4; ++k) {
        int idx4 = t + 128 * k;
        int c = idx4 >> 3, l4 = idx4 & 7;
        *(float4*)&xs[c * 32 + 4 * l4] = *(const float4*)&xb[(size_t)c * 32768 + 4 * l4];
    }
    {
        int o = t >> 1, hf = t & 1;
        const float* wbase = w + (size_t)(oh * 64) * 64;
        #pragma unroll
        for (int k = 0; k < 8; ++k) {
            float4 w4 = *(const float4*)&wbase[o * 64 + hf * 32 + 4 * k];
            int c = hf * 32 + 4 * k;
            wT[(c + 0) * 64 + o] = w4.x; wT[(c + 1) * 64 + o] = w4.y;
            wT[(c + 2) * 64 + o] = w4.z; wT[(c + 3) * 64 + o] = w4.w;
        }
    }
    __syncthreads();
    int ti = t >> 3, tj = t & 7;
    float acc[4][4] = {};
    #pragma unroll 8
    for (int c = 0; c < 64; ++c) {
        float4 xv = *(const float4*)&xs[c * 32 + 4 * tj];
        float4 w4 = *(const float4*)&wT[c * 64 + 4 * ti];
        float xa[4] = {xv.x, xv.y, xv.z, xv.w};
        float wa[4] = {w4.x, w4.y, w4.z, w4.w};
        #pragma unroll
        for (int oo = 0; oo < 4; ++oo)
            #pragma unroll
            for (int e = 0; e < 4; ++e) acc[oo][e] += wa[oo] * xa[e];
    }
    float* qn = qkv + (size_t)n * 4096 + oh * 2048;
    #pragma unroll
    for (int oo = 0; oo < 4; ++oo) {
        int o = 4 * ti + oo;
        *(float4*)(qn + o * 32 + 4 * tj) =
            make_float4(acc[oo][0], acc[oo][1], acc[oo][2], acc[oo][3]);
        float s1 = acc[oo][0] + acc[oo][1] + acc[oo][2] + acc[oo][3];
        float s2 = acc[oo][0]*acc[oo][0] + acc[oo][1]*acc[oo][1]
                 + acc[oo][2]*acc[oo][2] + acc[oo][3]*acc[oo][3];
        s1 = oct_sum(s1); s2 = oct_sum(s2);
        if (tj == 0) { statQ[o * 2] = s1; statQ[o * 2 + 1] = s2; }
    }
    __syncthreads();
    if (t < 128) {
        int ch = oh * 64 + (t >> 1);
        atomicAdd(&sqkv[((t & 1) ? 128 : 0) + ch], statQ[t]);
    }
}

// ---------------- K2: sim stats via dot2 + MFMA qk ----------------
__global__ __launch_bounds__(512, 4) void k_sim(const float* __restrict__ qkv,
                                                const f16* __restrict__ gemb,
                                                const float* __restrict__ sqkv,
                                                const float* __restrict__ bqg,
                                                const float* __restrict__ bqb,
                                                float* __restrict__ psim) {
    __shared__ __attribute__((aligned(16))) f16 qkh[8][32 * 8];   // [p][c]
    __shared__ float statw[8][6];
    int t = threadIdx.x, wv = t >> 6, l = t & 63;
    int g = blockIdx.x & 7, nb = blockIdx.x >> 3;
    int n = nb * 8 + wv;
    int li = l & 31, h = l >> 5;
    const unsigned* eT2u = (const unsigned*)gemb;
    {
        int ch = l >> 3, i0 = (l & 7) * 4;
        const float* qn = qkv + (size_t)n * 4096 + g * 512;
        float4 q4 = *(const float4*)(qn + ch * 32 + i0);
        int cc = g * 16 + ch;
        float mu = sqkv[cc] * (1.0f / 65536.0f);
        float var = sqkv[128 + cc] * (1.0f / 65536.0f) - mu * mu;
        float aa = bqg[cc] * rsqrtf(var + 1e-5f);
        float bb = bqb[cc] - mu * aa;
        qkh[wv][(i0 + 0) * 8 + ch] = (f16)(aa * q4.x + bb);
        qkh[wv][(i0 + 1) * 8 + ch] = (f16)(aa * q4.y + bb);
        qkh[wv][(i0 + 2) * 8 + ch] = (f16)(aa * q4.z + bb);
        qkh[wv][(i0 + 3) * 8 + ch] = (f16)(aa * q4.w + bb);
    }
    __syncthreads();
    unsigned uq[2][4], uk[2][4];
    float sqe = 0, sqe2 = 0, ske = 0, ske2 = 0;
    #pragma unroll
    for (int s = 0; s < 2; ++s) {
        #pragma unroll
        for (int blk = 0; blk < 2; ++blk) {
            int p0 = 16 * s + 4 * h + 8 * blk;
            U4 e0 = ld4(eT2u + 0 * 1152 + li * 36 + p0);
            U4 e1 = ld4(eT2u + 1 * 1152 + li * 36 + p0);
            U4 e2 = ld4(eT2u + 2 * 1152 + li * 36 + p0);
            U4 e3 = ld4(eT2u + 3 * 1152 + li * 36 + p0);
            float qe[4], ke[4];
            #pragma unroll
            for (int e = 0; e < 4; ++e) {
                U4 qr = ld4((const unsigned*)&qkh[wv][(p0 + e) * 8]);
                qe[e] = fdot2u(qr.a[0], e0.a[e], fdot2u(qr.a[1], e1.a[e], 0.f));
                ke[e] = fdot2u(qr.a[2], e2.a[e], fdot2u(qr.a[3], e3.a[e], 0.f));
                sqe += qe[e]; sqe2 += qe[e] * qe[e];
                ske += ke[e]; ske2 += ke[e] * ke[e];
            }
            uq[s][2 * blk + 0] = pkrtz(qe[0], qe[1]);
            uq[s][2 * blk + 1] = pkrtz(qe[2], qe[3]);
            uk[s][2 * blk + 0] = pkrtz(ke[0], ke[1]);
            uk[s][2 * blk + 1] = pkrtz(ke[2], ke[3]);
        }
    }
    F8 fq0, fq1, fk0, fk1;
    fq0.u[0]=uq[0][0]; fq0.u[1]=uq[0][1]; fq0.u[2]=uq[0][2]; fq0.u[3]=uq[0][3];
    fq1.u[0]=uq[1][0]; fq1.u[1]=uq[1][1]; fq1.u[2]=uq[1][2]; fq1.u[3]=uq[1][3];
    fk0.u[0]=uk[0][0]; fk0.u[1]=uk[0][1]; fk0.u[2]=uk[0][2]; fk0.u[3]=uk[0][3];
    fk1.u[0]=uk[1][0]; fk1.u[1]=uk[1][1]; fk1.u[2]=uk[1][2]; fk1.u[3]=uk[1][3];
    f32x16 D = {};
    D = __builtin_amdgcn_mfma_f32_32x32x16_f16(fk0.v, fq0.v, D, 0, 0, 0);
    D = __builtin_amdgcn_mfma_f32_32x32x16_f16(fk1.v, fq1.v, D, 0, 0, 0);
    float s1 = 0, s2 = 0;
    #pragma unroll
    for (int r = 0; r < 16; ++r) { s1 += D[r]; s2 += D[r] * D[r]; }
    s1 = sum64(s1);   s2 = sum64(s2);
    sqe = sum64(sqe); sqe2 = sum64(sqe2);
    ske = sum64(ske); ske2 = sum64(ske2);
    if (l == 0) {
        statw[wv][0] = s1;  statw[wv][1] = s2;
        statw[wv][2] = sqe; statw[wv][3] = sqe2;
        statw[wv][4] = ske; statw[wv][5] = ske2;
    }
    __syncthreads();
    if (t < 6) {
        float tot = 0;
        #pragma unroll
        for (int w2 = 0; w2 < 8; ++w2) tot += statw[w2][t];
        psim[blockIdx.x * 8 + t] = tot;
    }
}

// ---------------- K3: reduce sim partials ----------------
__global__ __launch_bounds__(64) void red_sim(const float* __restrict__ psim,
                                              float* __restrict__ ssim) {
    int t = threadIdx.x;
    if (t >= 48) return;
    int g = t / 6, s = t % 6;
    float acc = 0;
    #pragma unroll 8
    for (int nb = 0; nb < 256; ++nb) acc += psim[(nb * 8 + g) * 8 + s];
    const int base[6] = {0, 24, 8, 32, 16, 40};
    ssim[base[s] + g] = acc;
}

// ---------------- K4: attention (dot2 + MFMA qk + MFMA PV) ----------------
__global__ __launch_bounds__(512, 4) void k_attn(const float* __restrict__ qkv,
                                                 const f16* __restrict__ gemb,
                                                 const float* __restrict__ sqkv,
                                                 const float* __restrict__ bqg,
                                                 const float* __restrict__ bqb,
                                                 const float* __restrict__ ssim,
                                                 const float* __restrict__ bsg,
                                                 const float* __restrict__ bsb,
                                                 float* __restrict__ oraw,
                                                 float* __restrict__ sout) {
    __shared__ __attribute__((aligned(16))) f16 qkh[8][32 * 8];   // [p][c] q/k-hat
    __shared__ __attribute__((aligned(16))) f16 vh[8][8 * 36];    // [c][j] v-hat
    __shared__ float statw[8][32];
    int t = threadIdx.x, wv = t >> 6, l = t & 63;
    int g = blockIdx.x & 7, nb = blockIdx.x >> 3;
    int n = nb * 8 + wv;
    int li = l & 31, h = l >> 5;
    const unsigned* eT2u = (const unsigned*)gemb;
    const unsigned* eP2u = eT2u + 4608;
    const f16* ePvh = gemb + 18432;
    float aQK, aQE, aKE, csum;
    {
        float m0 = ssim[g] * (1.0f / 2097152.0f);
        float v0 = ssim[24 + g] * (1.0f / 2097152.0f) - m0 * m0;
        aQK = bsg[g] * rsqrtf(v0 + 1e-5f);
        float b0 = bsb[g] - m0 * aQK;
        float m1 = ssim[8 + g] * (1.0f / 2097152.0f);
        float v1 = ssim[32 + g] * (1.0f / 2097152.0f) - m1 * m1;
        aQE = bsg[8 + g] * rsqrtf(v1 + 1e-5f);
        float b1 = bsb[8 + g] - m1 * aQE;
        float m2 = ssim[16 + g] * (1.0f / 2097152.0f);
        float v2 = ssim[40 + g] * (1.0f / 2097152.0f) - m2 * m2;
        aKE = bsg[16 + g] * rsqrtf(v2 + 1e-5f);
        float b2 = bsb[16 + g] - m2 * aKE;
        csum = b0 + b1 + b2;
    }
    {
        int ch = l >> 3, i0 = (l & 7) * 4;
        const float* qn = qkv + (size_t)n * 4096 + g * 512;
        float4 q4 = *(const float4*)(qn + ch * 32 + i0);
        int cc = g * 16 + ch;
        float mu = sqkv[cc] * (1.0f / 65536.0f);
        float var = sqkv[128 + cc] * (1.0f / 65536.0f) - mu * mu;
        float aa = bqg[cc] * rsqrtf(var + 1e-5f);
        float bb = bqb[cc] - mu * aa;
        qkh[wv][(i0 + 0) * 8 + ch] = (f16)(aa * q4.x + bb);
        qkh[wv][(i0 + 1) * 8 + ch] = (f16)(aa * q4.y + bb);
        qkh[wv][(i0 + 2) * 8 + ch] = (f16)(aa * q4.z + bb);
        qkh[wv][(i0 + 3) * 8 + ch] = (f16)(aa * q4.w + bb);
        float4 v4 = *(const float4*)(qn + (8 + ch) * 32 + i0);
        int cv = g * 16 + 8 + ch;
        float muv = sqkv[cv] * (1.0f / 65536.0f);
        float varv = sqkv[128 + cv] * (1.0f / 65536.0f) - muv * muv;
        float av = bqg[cv] * rsqrtf(varv + 1e-5f);
        float bv = bqb[cv] - muv * av;
        vh[wv][ch * 36 + i0 + 0] = (f16)(av * v4.x + bv);
        vh[wv][ch * 36 + i0 + 1] = (f16)(av * v4.y + bv);
        vh[wv][ch * 36 + i0 + 2] = (f16)(av * v4.z + bv);
        vh[wv][ch * 36 + i0 + 3] = (f16)(av * v4.w + bv);
    }
    __syncthreads();
    // ---- qk fragments via dot2, then MFMA: D[r] = qk[i=li][j=crow(r)] ----
    unsigned uq[2][4], uk[2][4];
    #pragma unroll
    for (int s = 0; s < 2; ++s) {
        #pragma unroll
        for (int blk = 0; blk < 2; ++blk) {
            int p0 = 16 * s + 4 * h + 8 * blk;
            U4 e0 = ld4(eT2u + 0 * 1152 + li * 36 + p0);
            U4 e1 = ld4(eT2u + 1 * 1152 + li * 36 + p0);
            U4 e2 = ld4(eT2u + 2 * 1152 + li * 36 + p0);
            U4 e3 = ld4(eT2u + 3 * 1152 + li * 36 + p0);
            float qe[4], ke[4];
            #pragma unroll
            for (int e = 0; e < 4; ++e) {
                U4 qr = ld4((const unsigned*)&qkh[wv][(p0 + e) * 8]);
                qe[e] = fdot2u(qr.a[0], e0.a[e], fdot2u(qr.a[1], e1.a[e], 0.f));
                ke[e] = fdot2u(qr.a[2], e2.a[e], fdot2u(qr.a[3], e3.a[e], 0.f));
            }
            uq[s][2 * blk + 0] = pkrtz(qe[0], qe[1]);
            uq[s][2 * blk + 1] = pkrtz(qe[2], qe[3]);
            uk[s][2 * blk + 0] = pkrtz(ke[0], ke[1]);
            uk[s][2 * blk + 1] = pkrtz(ke[2], ke[3]);
        }
    }
    F8 fq0, fq1, fk0, fk1;
    fq0.u[0]=uq[0][0]; fq0.u[1]=uq[0][1]; fq0.u[2]=uq[0][2]; fq0.u[3]=uq[0][3];
    fq1.u[0]=uq[1][0]; fq1.u[1]=uq[1][1]; fq1.u[2]=uq[1][2]; fq1.u[3]=uq[1][3];
    fk0.u[0]=uk[0][0]; fk0.u[1]=uk[0][1]; fk0.u[2]=uk[0][2]; fk0.u[3]=uk[0][3];
    fk1.u[0]=uk[1][0]; fk1.u[1]=uk[1][1]; fk1.u[2]=uk[1][2]; fk1.u[3]=uk[1][3];
    f32x16 D = {};
    D = __builtin_amdgcn_mfma_f32_32x32x16_f16(fk0.v, fq0.v, D, 0, 0, 0);
    D = __builtin_amdgcn_mfma_f32_32x32x16_f16(fk1.v, fq1.v, D, 0, 0, 0);
    // ---- scores + softmax (score terms via dot2 on P-orientation tables) ----
    U4 qhv = ld4((const unsigned*)&qkh[wv][li * 8]);
    float pe[16];
    #pragma unroll
    for (int rq = 0; rq < 4; ++rq) {
        int j0 = 8 * rq + 4 * h;
        U4 a0 = ld4(eP2u + 0 * 1152 + li * 36 + j0);
        U4 a1 = ld4(eP2u + 1 * 1152 + li * 36 + j0);
        U4 a2 = ld4(eP2u + 2 * 1152 + li * 36 + j0);
        U4 a3 = ld4(eP2u + 3 * 1152 + li * 36 + j0);
        #pragma unroll
        for (int e = 0; e < 4; ++e) {
            float qe4 = fdot2u(qhv.a[0], a0.a[e], fdot2u(qhv.a[1], a1.a[e], 0.f));
            float ke4 = fdot2u(qhv.a[2], a2.a[e], fdot2u(qhv.a[3], a3.a[e], 0.f));
            pe[4 * rq + e] = __expf(aQK * D[4 * rq + e] + aQE * qe4 + aKE * ke4 + csum);
        }
    }
    float se = 0;
    #pragma unroll
    for (int r = 0; r < 16; ++r) se += pe[r];
    se += __shfl_xor(se, 32);
    float inv = __frcp_rn(se);
    #pragma unroll
    for (int r = 0; r < 16; ++r) pe[r] *= inv;
    // ---- P / V fragments ----
    F8 fp0, fp1, fv0, fv1;
    fp0.u[0] = pkrtz(pe[0], pe[1]);  fp0.u[1] = pkrtz(pe[2], pe[3]);
    fp0.u[2] = pkrtz(pe[4], pe[5]);  fp0.u[3] = pkrtz(pe[6], pe[7]);
    fp1.u[0] = pkrtz(pe[8], pe[9]);  fp1.u[1] = pkrtz(pe[10], pe[11]);
    fp1.u[2] = pkrtz(pe[12], pe[13]); fp1.u[3] = pkrtz(pe[14], pe[15]);
    {
        const f16* vb = &vh[wv][(li & 7) * 36];
        uint2 va0 = *(const uint2*)(vb + 4 * h);
        uint2 vb0 = *(const uint2*)(vb + 4 * h + 8);
        uint2 va1 = *(const uint2*)(vb + 16 + 4 * h);
        uint2 vb1 = *(const uint2*)(vb + 16 + 4 * h + 8);
        if (li >= 8) {
            va0 = make_uint2(0, 0); vb0 = make_uint2(0, 0);
            va1 = make_uint2(0, 0); vb1 = make_uint2(0, 0);
        }
        fv0.u[0] = va0.x; fv0.u[1] = va0.y; fv0.u[2] = vb0.x; fv0.u[3] = vb0.y;
        fv1.u[0] = va1.x; fv1.u[1] = va1.y; fv1.u[2] = vb1.x; fv1.u[3] = vb1.y;
    }
    f32x16 D2 = {};
    D2 = __builtin_amdgcn_mfma_f32_32x32x16_f16(fv0.v, fp0.v, D2, 0, 0, 0);
    D2 = __builtin_amdgcn_mfma_f32_32x32x16_f16(fv1.v, fp1.v, D2, 0, 0, 0);
    // ---- ame via dot2 (reuse packed P pairs) ----
    unsigned up[2][4] = {{fp0.u[0], fp0.u[1], fp0.u[2], fp0.u[3]},
                         {fp1.u[0], fp1.u[1], fp1.u[2], fp1.u[3]}};
    float ame[8];
    #pragma unroll
    for (int c = 0; c < 8; ++c) {
        const f16* er = ePvh + (c * 32 + li) * 36;
        float acc = 0;
        #pragma unroll
        for (int s = 0; s < 2; ++s) {
            #pragma unroll
            for (int dd = 0; dd < 2; ++dd) {
                uint2 ev = *(const uint2*)(er + 16 * s + 8 * dd + 4 * h);
                acc = fdot2u(up[s][2 * dd + 0], ev.x, acc);
                acc = fdot2u(up[s][2 * dd + 1], ev.y, acc);
            }
        }
        ame[c] = acc + __shfl_xor(acc, 32);
    }
    // ---- write oraw + out stats ----
    float* on = oraw + (size_t)n * 4096 + g * 512;
    #pragma unroll
    for (int e = 0; e < 4; ++e) {
        int c = e + 4 * h;
        float amv = D2[e];
        float amev = ame[c];
        on[(2 * c) * 32 + li] = amv;
        on[(2 * c + 1) * 32 + li] = amev;
        float x1 = sum32(amv), x2 = sum32(amv * amv);
        float y1 = sum32(amev), y2 = sum32(amev * amev);
        if (li == 0) {
            statw[wv][(2 * c) * 2 + 0] = x1;     statw[wv][(2 * c) * 2 + 1] = x2;
            statw[wv][(2 * c + 1) * 2 + 0] = y1; statw[wv][(2 * c + 1) * 2 + 1] = y2;
        }
    }
    __syncthreads();
    if (t < 32) {
        float tot = 0;
        #pragma unroll
        for (int w2 = 0; w2 < 8; ++w2) tot += statw[w2][t];
        int u = t >> 1;
        int och = g * 16 + u;
        atomicAdd(&sout[((t & 1) ? 128 : 0) + och], tot);
    }
}

// ---------------- K5: out BN (inline affine) + pair-sum + transpose ----------------
__global__ __launch_bounds__(256) void k_out(const float* __restrict__ oraw,
                                             const float* __restrict__ sout,
                                             const float* __restrict__ bog,
                                             const float* __restrict__ bob,
                                             float* __restrict__ out) {
    int gid = blockIdx.x * 256 + threadIdx.x;
    int l4 = gid & 7;
    int rest = gid >> 3;
    int w2 = rest & 31; rest >>= 5;
    int hh = rest & 31; rest >>= 5;
    int oc = rest & 63;
    int b = rest >> 6;
    int n = b * 1024 + hh * 32 + w2;
    int c0 = 2 * oc, c1 = 2 * oc + 1;
    float mu0 = sout[c0] * (1.0f / 65536.0f);
    float v0 = sout[128 + c0] * (1.0f / 65536.0f) - mu0 * mu0;
    float a0 = bog[c0] * rsqrtf(v0 + 1e-5f);
    float b0 = bob[c0] - mu0 * a0;
    float mu1 = sout[c1] * (1.0f / 65536.0f);
    float v1 = sout[128 + c1] * (1.0f / 65536.0f) - mu1 * mu1;
    float a1 = bog[c1] * rsqrtf(v1 + 1e-5f);
    float b1 = bob[c1] - mu1 * a1;
    float cc = b0 + b1;
    const float4 r0 = *(const float4*)(oraw + (size_t)n * 4096 + oc * 64 + l4 * 4);
    const float4 r1 = *(const float4*)(oraw + (size_t)n * 4096 + oc * 64 + 32 + l4 * 4);
    float4 o;
    o.x = a0 * r0.x + a1 * r1.x + cc;
    o.y = a0 * r0.y + a1 * r1.y + cc;
    o.z = a0 * r0.z + a1 * r1.z + cc;
    o.w = a0 * r0.w + a1 * r1.w + cc;
    *((float4*)out + gid) = o;
}

extern "C" void kernel_launch(void* const* d_in, const int* in_sizes, int n_in,
                              void* d_out, int out_size, void* d_ws, size_t ws_size,
                              hipStream_t stream) {
    const float* x   = (const float*)d_in[0];
    const float* w   = (const float*)d_in[1];
    const float* bqg = (const float*)d_in[2];
    const float* bqb = (const float*)d_in[3];
    const float* bsg = (const float*)d_in[4];
    const float* bsb = (const float*)d_in[5];
    const float* bog = (const float*)d_in[6];
    const float* bob = (const float*)d_in[7];
    const float* rel = (const float*)d_in[8];

    float* ws   = (float*)d_ws;
    float* qkv  = ws;                    // 8,388,608 f32
    float* oraw = ws + 8388608;          // 8,388,608 f32
    float* psim = oraw;                  // 2048*8 f32, consumed before k_attn writes oraw
    f16* gemb = (f16*)(ws + 16777216);   // 27,648 halves (13,824 f32 slots)
    float* stats = ws + 16777216 + 13824;
    float* sqkv = stats;        // 256
    float* ssim = stats + 256;  // 48
    float* sout = stats + 304;  // 256

    hipMemsetAsync(stats, 0, 560 * sizeof(float), stream);

    k_emb<<<1, 512, 0, stream>>>(rel, gemb);
    k_qkv<<<4096, 128, 0, stream>>>(x, w, qkv, sqkv);
    k_sim<<<2048, 512, 0, stream>>>(qkv, gemb, sqkv, bqg, bqb, psim);
    red_sim<<<1, 64, 0, stream>>>(psim, ssim);
    k_attn<<<2048, 512, 0, stream>>>(qkv, gemb, sqkv, bqg, bqb, ssim, bsg, bsb, oraw, sout);
    k_out<<<4096, 256, 0, stream>>>(oraw, sout, bog, bob, (float*)d_out);
}